// Round 1
// baseline (9069.648 us; speedup 1.0000x reference)
//
#include <hip/hip_runtime.h>

// Problem constants
#define NB   64          // B
#define NT   256         // T
#define NC   512         // C
#define NK   1024        // K codes per layer
#define NQ   6           // layers
#define NROWS (NB*NT)    // 16384
#define QOUT_ELEMS 8388608   // B*C*T
#define IDX_ELEMS  98304     // B*T*Q

// ws layout (bytes)
#define WS_BEST   0           // u64[16384]      (128 KiB)
#define WS_COUNTS 131072      // u32[1024]       (4 KiB)
#define WS_CSUM   135168      // float[6] raw commit sums
#define WS_CMEAN  135192      // float[6]
#define WS_PERP   135216      // float[6]
#define WS_CBN    135296      // float[6*1024] half-norms
// total 159872 bytes

// -------- codebook half-norms for all layers --------
__global__ void vq_cbnorm(const float* __restrict__ cb, float* __restrict__ cbn) {
    int lane = threadIdx.x & 63, wid = threadIdx.x >> 6;
    int code = blockIdx.x * 4 + wid;                    // grid 1536 -> 6144 codes
    const float4* p = (const float4*)(cb + (size_t)code * NC);
    float4 v1 = p[lane], v2 = p[lane + 64];
    float s = v1.x*v1.x + v1.y*v1.y + v1.z*v1.z + v1.w*v1.w
            + v2.x*v2.x + v2.y*v2.y + v2.z*v2.z + v2.w*v2.w;
    #pragma unroll
    for (int off = 32; off; off >>= 1) s += __shfl_down(s, off, 64);
    if (lane == 0) cbn[code] = 0.5f * s;
}

// -------- fused distance GEMM + argmin --------
// grid (128 rowblocks, 2 codegroups), 256 threads.
// Block tile: 128 rows x 128 codes, micro-tile 8x8, C-chunk 32.
// score = ||cb||^2/2 - x.cb  (monotone in true distance)
__global__ __launch_bounds__(256) void vq_dist(
    const float* __restrict__ src,     // residual (B,C,T)
    const float* __restrict__ cb,      // layer codebook (K,C)
    const float* __restrict__ cbn,     // layer half-norms (K)
    unsigned long long* __restrict__ best,
    unsigned int* __restrict__ counts,
    float* __restrict__ commit_slot)
{
    const int rb  = blockIdx.x;        // 0..127
    const int cg  = blockIdx.y;        // 0..1
    const int tid = threadIdx.x;
    // fold zero-init of counts/commit for the NEXT (update) kernel into block (0,0)
    if (rb == 0 && cg == 0) {
        for (int i = tid; i < NK; i += 256) counts[i] = 0u;
        if (tid == 0) *commit_slot = 0.f;
    }
    __shared__ __align__(16) float xs[128][36];   // [t_local][c_local]
    __shared__ __align__(16) float bs[128][36];   // [k_local][c_local]
    __shared__ float red_s[128][17];
    __shared__ int   red_i[128][17];

    const int tcol = tid & 15;         // code group (8 codes, stride 16)
    const int trow = tid >> 4;         // row group (8 rows contiguous)
    const int b  = rb >> 1;
    const int t0 = (rb & 1) << 7;      // t tile of 128
    const float* xbase = src + (size_t)b * (NC * NT) + t0;

    float bsc[8]; int bki[8];
    #pragma unroll
    for (int i = 0; i < 8; ++i) { bsc[i] = 3.402823466e38f; bki[i] = 0; }

    for (int kt = 0; kt < 4; ++kt) {
        const int kbase = cg * 512 + kt * 128;
        float acc[8][8];
        #pragma unroll
        for (int i = 0; i < 8; ++i)
            #pragma unroll
            for (int j = 0; j < 8; ++j) acc[i][j] = 0.f;

        for (int cc = 0; cc < NC; cc += 32) {
            __syncthreads();
            // stage A: 128 t x 32 c from (B,C,T): coalesced along t
            #pragma unroll
            for (int i = 0; i < 4; ++i) {
                int f   = tid + (i << 8);     // 0..1023
                int c_l = f >> 5;             // 0..31
                int tf  = f & 31;             // 0..31 (t in units of 4)
                float4 v = *(const float4*)(xbase + (size_t)(cc + c_l) * NT + (tf << 2));
                xs[(tf << 2) + 0][c_l] = v.x;
                xs[(tf << 2) + 1][c_l] = v.y;
                xs[(tf << 2) + 2][c_l] = v.z;
                xs[(tf << 2) + 3][c_l] = v.w;
            }
            // stage B: 128 k x 32 c from (K,C): coalesced along c
            #pragma unroll
            for (int i = 0; i < 4; ++i) {
                int f   = tid + (i << 8);
                int k_l = f >> 3;             // 0..127
                int cs  = f & 7;              // 0..7 (c in units of 4)
                float4 v = *(const float4*)(cb + (size_t)(kbase + k_l) * NC + cc + (cs << 2));
                *(float4*)&bs[k_l][cs << 2] = v;
            }
            __syncthreads();
            #pragma unroll
            for (int c4 = 0; c4 < 8; ++c4) {
                float4 a[8], bv[8];
                #pragma unroll
                for (int i = 0; i < 8; ++i)
                    a[i] = *(const float4*)&xs[trow * 8 + i][c4 << 2];
                #pragma unroll
                for (int j = 0; j < 8; ++j)
                    bv[j] = *(const float4*)&bs[tcol + 16 * j][c4 << 2];
                #pragma unroll
                for (int i = 0; i < 8; ++i)
                    #pragma unroll
                    for (int j = 0; j < 8; ++j)
                        acc[i][j] += a[i].x * bv[j].x + a[i].y * bv[j].y
                                   + a[i].z * bv[j].z + a[i].w * bv[j].w;
            }
        }
        // epilogue: score + running argmin (ascending j keeps lowest k on ties)
        #pragma unroll
        for (int j = 0; j < 8; ++j) {
            int kg = kbase + tcol + 16 * j;
            float cn = cbn[kg];
            #pragma unroll
            for (int i = 0; i < 8; ++i) {
                float s = cn - acc[i][j];
                if (s < bsc[i]) { bsc[i] = s; bki[i] = kg; }
            }
        }
    }
    __syncthreads();
    #pragma unroll
    for (int i = 0; i < 8; ++i) {
        red_s[trow * 8 + i][tcol] = bsc[i];
        red_i[trow * 8 + i][tcol] = bki[i];
    }
    __syncthreads();
    if (tid < 128) {
        float s = red_s[tid][0]; int k = red_i[tid][0];
        #pragma unroll
        for (int e = 1; e < 16; ++e) {
            float s2 = red_s[tid][e]; int k2 = red_i[tid][e];
            if (s2 < s || (s2 == s && k2 < k)) { s = s2; k = k2; }
        }
        unsigned int u = __float_as_uint(s);
        u = (u & 0x80000000u) ? ~u : (u | 0x80000000u);   // order-preserving map
        unsigned long long key = ((unsigned long long)u << 32) | (unsigned int)k;
        atomicMin(&best[(size_t)rb * 128 + tid], key);
    }
}

// -------- gather + residual update + commit + histogram + index output --------
// grid 256 blocks (64 rows each), 256 threads
__global__ __launch_bounds__(256) void vq_update(
    const float* __restrict__ src,    // residual before (x for q=0), (B,C,T)
    float* __restrict__ dst,          // residual after (d_out qout slot)
    const float* __restrict__ cb,
    const unsigned long long* __restrict__ best,
    unsigned int* __restrict__ counts,
    float* __restrict__ commit_slot,
    float* __restrict__ out_idx,
    int q)
{
    const int rb = blockIdx.x, tid = threadIdx.x;
    const int b = rb >> 2, t0 = (rb & 3) << 6;
    const int row0 = rb * 64;
    __shared__ int s_idx[64];
    __shared__ __align__(16) float qt[64][68];   // [c_local][t_local]
    __shared__ float wsum[4];
    if (tid < 64) {
        unsigned long long key = best[row0 + tid];
        int idx = (int)(key & 0xFFFFFFFFull);
        s_idx[tid] = idx;
        out_idx[(size_t)(row0 + tid) * NQ + q] = (float)idx;
        atomicAdd(&counts[idx], 1u);
    }
    __syncthreads();
    float csum = 0.f;
    const size_t base = (size_t)b * (NC * NT) + t0;
    for (int ct = 0; ct < 8; ++ct) {             // c chunks of 64
        if (ct) __syncthreads();
        // fill qt with cb[idx[r]][ct*64 .. +64), transposed to [c][t]
        #pragma unroll
        for (int i = 0; i < 4; ++i) {
            int f = tid + (i << 8);              // 0..1023
            int r = f >> 4, cf = f & 15;
            float4 v = *(const float4*)(cb + (size_t)s_idx[r] * NC + ct * 64 + (cf << 2));
            qt[(cf << 2) + 0][r] = v.x;
            qt[(cf << 2) + 1][r] = v.y;
            qt[(cf << 2) + 2][r] = v.z;
            qt[(cf << 2) + 3][r] = v.w;
        }
        __syncthreads();
        // residual RMW, coalesced along t
        #pragma unroll
        for (int i = 0; i < 4; ++i) {
            int f = tid + (i << 8);
            int c_l = f >> 4, tf = f & 15;
            size_t o = base + (size_t)(ct * 64 + c_l) * NT + (tf << 2);
            float4 r4 = *(const float4*)(src + o);
            float4 q4 = *(const float4*)&qt[c_l][tf << 2];
            float4 n;
            n.x = r4.x - q4.x; n.y = r4.y - q4.y; n.z = r4.z - q4.z; n.w = r4.w - q4.w;
            *(float4*)(dst + o) = n;
            csum += n.x*n.x + n.y*n.y + n.z*n.z + n.w*n.w;
        }
    }
    #pragma unroll
    for (int off = 32; off; off >>= 1) csum += __shfl_down(csum, off, 64);
    if ((tid & 63) == 0) wsum[tid >> 6] = csum;
    __syncthreads();
    if (tid == 0) atomicAdd(commit_slot, wsum[0] + wsum[1] + wsum[2] + wsum[3]);
}

// -------- perplexity + commit mean per layer; final means at q==5 --------
__global__ void vq_stats(const unsigned int* __restrict__ counts,
                         float* __restrict__ csum, float* __restrict__ cmean,
                         float* __restrict__ perp, float* __restrict__ out_tail, int q)
{
    const int tid = threadIdx.x;   // 1024
    float p = (float)counts[tid] * (1.f / (float)NROWS);
    float v = p * logf(p + 1e-7f);
    #pragma unroll
    for (int off = 32; off; off >>= 1) v += __shfl_down(v, off, 64);
    __shared__ float red[16];
    if ((tid & 63) == 0) red[tid >> 6] = v;
    __syncthreads();
    if (tid == 0) {
        float S = 0.f;
        #pragma unroll
        for (int i = 0; i < 16; ++i) S += red[i];
        perp[q]  = expf(-S);
        cmean[q] = csum[q] * (1.f / ((float)NROWS * (float)NC));
        if (q == NQ - 1) {
            float mc = 0.f, mp = 0.f;
            for (int i = 0; i < NQ; ++i) { mc += cmean[i]; mp += perp[i]; }
            out_tail[0] = mc / (float)NQ;
            out_tail[1] = mp / (float)NQ;
        }
    }
}

// -------- qout = x - residual_final (elementwise, in place) --------
__global__ void vq_finalize(const float* __restrict__ x, float* __restrict__ res, int n4) {
    int i = blockIdx.x * blockDim.x + threadIdx.x;
    if (i < n4) {
        float4 a = ((const float4*)x)[i];
        float4 r = ((float4*)res)[i];
        float4 o;
        o.x = a.x - r.x; o.y = a.y - r.y; o.z = a.z - r.z; o.w = a.w - r.w;
        ((float4*)res)[i] = o;
    }
}

extern "C" void kernel_launch(void* const* d_in, const int* in_sizes, int n_in,
                              void* d_out, int out_size, void* d_ws, size_t ws_size,
                              hipStream_t stream) {
    const float* x  = (const float*)d_in[0];
    const float* cb = (const float*)d_in[1];       // (Q,K,C)
    float* out      = (float*)d_out;
    float* res      = out;                          // residual lives in qout slot
    float* out_idx  = out + QOUT_ELEMS;
    float* out_tail = out + QOUT_ELEMS + IDX_ELEMS;
    char* ws = (char*)d_ws;
    unsigned long long* best = (unsigned long long*)(ws + WS_BEST);
    unsigned int* counts = (unsigned int*)(ws + WS_COUNTS);
    float* csum  = (float*)(ws + WS_CSUM);
    float* cmean = (float*)(ws + WS_CMEAN);
    float* perp  = (float*)(ws + WS_PERP);
    float* cbn   = (float*)(ws + WS_CBN);

    vq_cbnorm<<<1536, 256, 0, stream>>>(cb, cbn);
    for (int q = 0; q < NQ; ++q) {
        hipMemsetAsync(best, 0xFF, NROWS * sizeof(unsigned long long), stream);
        const float* src = (q == 0) ? x : res;
        const float* cbq = cb + (size_t)q * NK * NC;
        vq_dist<<<dim3(128, 2), 256, 0, stream>>>(src, cbq, cbn + q * NK,
                                                  best, counts, csum + q);
        vq_update<<<256, 256, 0, stream>>>(src, res, cbq, best, counts,
                                           csum + q, out_idx, q);
        vq_stats<<<1, 1024, 0, stream>>>(counts, csum, cmean, perp, out_tail, q);
    }
    vq_finalize<<<8192, 256, 0, stream>>>(x, res, QOUT_ELEMS / 4);
}